// Round 10
// baseline (357.803 us; speedup 1.0000x reference)
//
#include <hip/hip_runtime.h>
#include <hip/hip_bf16.h>

#define T_TOK 4096
#define HDIM  1024
#define NEXP  8
#define IDIM  1408
#define ISDIM 2816

typedef short bf16x8 __attribute__((ext_vector_type(8)));
typedef float f32x4  __attribute__((ext_vector_type(4)));
typedef unsigned short u16;
typedef unsigned short u16x4 __attribute__((ext_vector_type(4)));
typedef unsigned short u16x8 __attribute__((ext_vector_type(8)));

typedef __attribute__((address_space(1))) const void gvoid;
typedef __attribute__((address_space(3))) void lvoid;

__device__ __forceinline__ u16 f2bf(float f) {
    union { float f; unsigned u; } c; c.f = f;
    unsigned r = (c.u + 0x7FFFu + ((c.u >> 16) & 1u)) >> 16;
    return (u16)r;
}
__device__ __forceinline__ float bf2f(u16 v) {
    union { unsigned u; float f; } c; c.u = (unsigned)v << 16; return c.f;
}
__device__ __forceinline__ void glds16(const u16* g, u16* l) {
    __builtin_amdgcn_global_load_lds((gvoid*)g, (lvoid*)l, 16, 0, 0);
}

// ---------------- routing: one wave per token (no atomics) ----------------
__global__ __launch_bounds__(256) void route_kernel(
    const float* __restrict__ X, const float* __restrict__ GW,
    const float* __restrict__ SEG,
    int* __restrict__ topk_e, float* __restrict__ topk_w,
    float* __restrict__ sgate)
{
    const int t = blockIdx.x * 4 + (threadIdx.x >> 6);
    const int lane = threadIdx.x & 63;
    float acc[NEXP];
    #pragma unroll
    for (int e = 0; e < NEXP; ++e) acc[e] = 0.f;
    float sacc = 0.f;
    const float* xr = X + (size_t)t * HDIM;
    for (int h = lane; h < HDIM; h += 64) {
        float xv = xr[h];
        f32x4 g0 = *(const f32x4*)(GW + (size_t)h * NEXP);
        f32x4 g1 = *(const f32x4*)(GW + (size_t)h * NEXP + 4);
        acc[0] += xv * g0[0]; acc[1] += xv * g0[1];
        acc[2] += xv * g0[2]; acc[3] += xv * g0[3];
        acc[4] += xv * g1[0]; acc[5] += xv * g1[1];
        acc[6] += xv * g1[2]; acc[7] += xv * g1[3];
        sacc += xv * SEG[h];
    }
    #pragma unroll
    for (int off = 32; off > 0; off >>= 1) {
        #pragma unroll
        for (int e = 0; e < NEXP; ++e) acc[e] += __shfl_down(acc[e], off);
        sacc += __shfl_down(sacc, off);
    }
    if (lane == 0) {
        int e0 = 0;
        #pragma unroll
        for (int e = 1; e < NEXP; ++e) if (acc[e] > acc[e0]) e0 = e;
        int e1 = (e0 == 0) ? 1 : 0;
        #pragma unroll
        for (int e = 0; e < NEXP; ++e)
            if (e != e0 && acc[e] > acc[e1]) e1 = e;
        float w0 = 1.f / (1.f + __expf(acc[e1] - acc[e0]));
        topk_e[t * 2]     = e0; topk_e[t * 2 + 1] = e1;
        topk_w[t * 2]     = w0; topk_w[t * 2 + 1] = 1.f - w0;
        sgate[t] = 1.f / (1.f + __expf(-sacc));
    }
}

// ---------------- histogram ----------------
__global__ __launch_bounds__(256) void hist_kernel(
    const int* __restrict__ topk_e, int* __restrict__ counts)
{
    __shared__ int h[NEXP];
    if (threadIdx.x < NEXP) h[threadIdx.x] = 0;
    __syncthreads();
    int i = blockIdx.x * 256 + threadIdx.x;
    atomicAdd(&h[topk_e[i]], 1);
    __syncthreads();
    if (threadIdx.x < NEXP) atomicAdd(&counts[threadIdx.x], h[threadIdx.x]);
}

__global__ void offsets_kernel(const int* __restrict__ counts,
                               int* __restrict__ seg_start,
                               int* __restrict__ cursors)
{
    if (threadIdx.x == 0) {
        int s = 0;
        for (int e = 0; e < NEXP; ++e) {
            seg_start[e] = s; cursors[e] = s; s += counts[e];
        }
    }
}

// ---------------- scatter ----------------
__global__ __launch_bounds__(256) void scatter_kernel(
    const int* __restrict__ topk_e,
    int* __restrict__ cursors, int* __restrict__ tok_ids,
    int* __restrict__ slot)
{
    const int i = blockIdx.x * 256 + threadIdx.x;
    const int lane = threadIdx.x & 63;
    const int e = topk_e[i];
    const unsigned long long lt = (1ull << lane) - 1ull;
    #pragma unroll
    for (int ex = 0; ex < NEXP; ++ex) {
        unsigned long long mask = __ballot(e == ex);
        if (mask == 0ull) continue;
        int cnt = __popcll(mask);
        int leader = __ffsll((long long)mask) - 1;
        int base_ = 0;
        if (lane == leader) base_ = atomicAdd(&cursors[ex], cnt);
        base_ = __shfl(base_, leader);
        if (e == ex) {
            int pos = base_ + __popcll(mask & lt);
            tok_ids[pos] = i >> 1;
            slot[i] = pos;
        }
    }
}

// ---------------- converts ----------------
__global__ __launch_bounds__(256) void cvt_x_kernel(
    const float* __restrict__ in, u16* __restrict__ out, int n)
{
    int i = (blockIdx.x * 256 + threadIdx.x) * 8;
    if (i < n) {
        f32x4 a = *(const f32x4*)(in + i);
        f32x4 b = *(const f32x4*)(in + i + 4);
        u16x8 o;
        #pragma unroll
        for (int j = 0; j < 4; ++j) { o[j] = f2bf(a[j]); o[j + 4] = f2bf(b[j]); }
        *(u16x8*)(out + i) = o;
    }
}

// fp32 [K][N] slices -> bf16 [N][K] (ilv=0) or 16-row gate/up interleave (ilv=1)
__global__ __launch_bounds__(256) void transpose_cvt(
    const float* __restrict__ in0, const float* __restrict__ in1,
    u16* __restrict__ out, int K, int N, int split, int ilv)
{
    const int z = blockIdx.z;
    const int e = (z < split) ? z : z - split;
    const float* in = (z < split) ? (in0 + (size_t)z * K * N)
                                  : (in1 + (size_t)(z - split) * K * N);
    u16* o = ilv ? (out + (size_t)e * 2 * N * K)
                 : (out + (size_t)z * N * K);
    const int radd = ilv ? ((z < split) ? 0 : 16) : 0;

    __shared__ float tile[64][65];
    const int n0 = blockIdx.x * 64, k0 = blockIdx.y * 64;
    const int tx = threadIdx.x & 15;
    const int ty = threadIdx.x >> 4;

    #pragma unroll
    for (int p = 0; p < 4; ++p) {
        int k = ty + p * 16;
        f32x4 v = *(const f32x4*)(in + (size_t)(k0 + k) * N + n0 + tx * 4);
        *(f32x4*)&tile[k][tx * 4] = v;
    }
    __syncthreads();
    #pragma unroll
    for (int p = 0; p < 4; ++p) {
        int n = ty + p * 16;
        u16x4 w;
        #pragma unroll
        for (int j = 0; j < 4; ++j) w[j] = f2bf(tile[tx * 4 + j][n]);
        int R = n0 + n;
        int orow = ilv ? (((R >> 4) * 32) + (R & 15) + radd) : R;
        *(u16x4*)(o + (size_t)orow * K + k0 + tx * 4) = w;
    }
}

// ====== 256x256xBK64, 8 waves, 4-phase/K-tile schedule (8-phase template family) ======
// LDS: A [2 buf][2 kh][256 rows][32 k] = 64KB, B same = 64KB (dynamic 128KB).
// Wave wv: wr=wv>>2 (m), wn=wv&3 (n). m-frag j: row (j>>2)*128 + wr*64 + (j&3)*16.
// n-frag i: row (i>>1)*128 + wn*32 + (i&1)*16.
// Phases per tile: P0{rd A(mh0,kh0)+B(kh0); stage kh0(t+1); bar; 16 MFMA; bar}
//                  P1{rd A(mh1,kh0); stage kh1(t+1); bar; 16 MFMA; vmcnt(8); bar}
//                  P2{rd A(mh0,kh1)+B(kh1); bar; 16 MFMA; bar}
//                  P3{rd A(mh1,kh1); bar; 16 MFMA; vmcnt(4); bar}

#define BAR() __builtin_amdgcn_s_barrier()
#define WCNT(n) asm volatile("s_waitcnt vmcnt(" #n ")" ::: "memory")

#define GSTAGE_KH0(wb) \
    glds16(aLo, &As[(wb) + tid * 8]); \
    glds16(aHi, &As[(wb) + 4096 + tid * 8]); \
    glds16(bLo, &Bs[(wb) + tid * 8]); \
    glds16(bHi, &Bs[(wb) + 4096 + tid * 8]);
#define GSTAGE_KH1(wb) \
    glds16(aLo + 32, &As[(wb) + 8192 + tid * 8]); \
    glds16(aHi + 32, &As[(wb) + 8192 + 4096 + tid * 8]); \
    glds16(bLo + 32, &Bs[(wb) + 8192 + tid * 8]); \
    glds16(bHi + 32, &Bs[(wb) + 8192 + 4096 + tid * 8]);

#define RD_A(rb, kh, j0) \
    _Pragma("unroll") for (int q = 0; q < 4; ++q) \
        av[q] = *(const bf16x8*)&As[(rb) + (kh) * 8192 + aofs[(j0) + q]];
#define RD_B(rb, kh) \
    _Pragma("unroll") for (int q = 0; q < 4; ++q) \
        bv[q] = *(const bf16x8*)&Bs[(rb) + (kh) * 8192 + bofs[q]];
#define MF16(ms) \
    __builtin_amdgcn_s_setprio(1); \
    _Pragma("unroll") for (int q = 0; q < 4; ++q) \
        _Pragma("unroll") for (int w = 0; w < 4; ++w) \
            acc[(ms) + q][w] = __builtin_amdgcn_mfma_f32_16x16x32_bf16(av[q], bv[w], acc[(ms) + q][w], 0, 0, 0); \
    __builtin_amdgcn_s_setprio(0);

#define GEMM_MAIN(NT) \
    GSTAGE_KH0(0) GSTAGE_KH1(0) \
    aLo += 64; aHi += 64; bLo += 64; bHi += 64; \
    WCNT(4); BAR(); \
    _Pragma("unroll 1") \
    for (int t = 0; t < (NT) - 1; ++t) { \
        const int rb = (t & 1) * 16384, wb = rb ^ 16384; \
        bf16x8 av[4], bv[4]; \
        RD_A(rb, 0, 0) RD_B(rb, 0) \
        GSTAGE_KH0(wb) \
        BAR(); MF16(0) BAR(); \
        RD_A(rb, 0, 4) \
        GSTAGE_KH1(wb) \
        BAR(); MF16(4) WCNT(8); BAR(); \
        RD_A(rb, 1, 0) RD_B(rb, 1) \
        BAR(); MF16(0) BAR(); \
        RD_A(rb, 1, 4) \
        BAR(); MF16(4) WCNT(4); BAR(); \
        aLo += 64; aHi += 64; bLo += 64; bHi += 64; \
    } \
    { \
        const int rb = (((NT) - 1) & 1) * 16384; \
        bf16x8 av[4], bv[4]; \
        RD_A(rb, 0, 0) RD_B(rb, 0) \
        BAR(); MF16(0) BAR(); \
        RD_A(rb, 0, 4) \
        BAR(); MF16(4) WCNT(0); BAR(); \
        RD_A(rb, 1, 0) RD_B(rb, 1) \
        BAR(); MF16(0) BAR(); \
        RD_A(rb, 1, 4) \
        BAR(); MF16(4) \
    }

// ---------------- merged gate+up GEMM (interleaved combined weights [2N][K]) ----------------
// grid(110, 16): zz<88 expert (e=zz&7, nz=zz>>3 of 11); zz>=88 shared (nz=zz-88 of 22)
__global__ __launch_bounds__(512, 2) void gemm_gu(
    const u16* __restrict__ A,
    const u16* __restrict__ WGUc, const u16* __restrict__ SGUc,
    u16* __restrict__ HoutE, u16* __restrict__ HoutS,
    const int* __restrict__ a_ids, const int* __restrict__ seg_start,
    const int* __restrict__ counts)
{
    extern __shared__ u16 lds[];
    u16* As = lds;
    u16* Bs = lds + 32768;

    const int zz = blockIdx.x;
    int cnt, base, n0c, N, nblk;
    const u16* Bsrc;
    u16* Hout;
    const int* ids;
    if (zz < 88) {
        int e = zz & 7;
        nblk = zz >> 3;
        cnt = counts[e]; base = seg_start[e];
        Bsrc = WGUc + (size_t)e * (2 * IDIM * HDIM);
        Hout = HoutE; N = IDIM; ids = a_ids;
    } else {
        nblk = zz - 88;
        cnt = T_TOK; base = 0;
        Bsrc = SGUc; Hout = HoutS; N = ISDIM; ids = nullptr;
    }
    n0c = nblk * 256;
    const int m0 = blockIdx.y * 256;
    if (m0 >= cnt) return;

    const int tid = threadIdx.x;
    const int srow = tid >> 2;
    const int sk = (tid & 3) * 8;
    int rlo = m0 + srow;       if (rlo >= cnt) rlo = cnt - 1;
    int rhi = m0 + 128 + srow; if (rhi >= cnt) rhi = cnt - 1;
    const int glo = ids ? ids[base + rlo] : (base + rlo);
    const int ghi = ids ? ids[base + rhi] : (base + rhi);
    const u16* aLo = A + (size_t)glo * HDIM + sk;
    const u16* aHi = A + (size_t)ghi * HDIM + sk;
    const u16* bLo = Bsrc + (size_t)(n0c + srow) * HDIM + sk;
    const u16* bHi = Bsrc + (size_t)(n0c + 128 + srow) * HDIM + sk;

    f32x4 acc[8][4];
    #pragma unroll
    for (int i = 0; i < 8; ++i)
        #pragma unroll
        for (int j = 0; j < 4; ++j) acc[i][j] = (f32x4){0.f, 0.f, 0.f, 0.f};

    const int lane = tid & 63;
    const int wv = tid >> 6;
    const int wr = wv >> 2;
    const int wn = wv & 3;
    const int l15 = lane & 15;
    const int ksl = lane >> 4;
    int aofs[8], bofs[4];
    #pragma unroll
    for (int j = 0; j < 8; ++j) {
        int mrow = (j >> 2) * 128 + wr * 64 + (j & 3) * 16;
        aofs[j] = (mrow + l15) * 32 + ksl * 8;
    }
    #pragma unroll
    for (int i = 0; i < 4; ++i) {
        int nrow = (i >> 1) * 128 + wn * 32 + (i & 1) * 16;
        bofs[i] = (nrow + l15) * 32 + ksl * 8;
    }

    GEMM_MAIN(16)   // K = 1024

    const int l4 = ksl * 4;
    #pragma unroll
    for (int j = 0; j < 8; ++j) {
        int mrow = (j >> 2) * 128 + wr * 64 + (j & 3) * 16;
        #pragma unroll
        for (int p = 0; p < 2; ++p) {
            f32x4 g = acc[j][2 * p], u = acc[j][2 * p + 1];
            int c = nblk * 128 + (p * 4 + wn) * 16 + l15;
            #pragma unroll
            for (int jj = 0; jj < 4; ++jj) {
                int r = m0 + mrow + l4 + jj;
                if (r < cnt) {
                    float hv = g[jj] / (1.f + __expf(-g[jj])) * u[jj];
                    Hout[(size_t)(base + r) * N + c] = f2bf(hv);
                }
            }
        }
    }
}

// ---------------- down GEMM 256x256: grid(40, 16) ----------------
// zz<32: expert (e=zz&7, n=(zz>>3)*256, K=1408, A=Hact) -> store Dexp
// zz in [32,40): shared (idx=zz-32: n=(idx&3)*256, kc=idx>>2) -> atomicAdd Out
__global__ __launch_bounds__(512, 2) void gemm_down(
    const u16* __restrict__ AE, const u16* __restrict__ AS,
    const u16* __restrict__ WDt, const u16* __restrict__ SDt,
    float* __restrict__ DexpO, float* __restrict__ OutS,
    const int* __restrict__ seg_start, const int* __restrict__ counts)
{
    extern __shared__ u16 lds[];
    u16* As = lds;
    u16* Bs = lds + 32768;

    const int zz = blockIdx.x;
    const bool shr = (zz >= 32);
    int n0, cnt, base, kst;
    size_t koff;
    const u16 *Asrc, *Bsrc;
    if (!shr) {
        int e = zz & 7;
        n0 = (zz >> 3) * 256;
        cnt = counts[e]; base = seg_start[e];
        Asrc = AE; Bsrc = WDt + (size_t)e * (HDIM * IDIM);
        kst = IDIM; koff = 0;
    } else {
        int idx = zz - 32;
        n0 = (idx & 3) * 256;
        cnt = T_TOK; base = 0;
        Asrc = AS; Bsrc = SDt;
        kst = ISDIM; koff = (size_t)(idx >> 2) * 1408;
    }
    const int m0 = blockIdx.y * 256;
    if (m0 >= cnt) return;

    const int tid = threadIdx.x;
    const int srow = tid >> 2;
    const int sk = (tid & 3) * 8;
    int rlo = m0 + srow;       if (rlo >= cnt) rlo = cnt - 1;
    int rhi = m0 + 128 + srow; if (rhi >= cnt) rhi = cnt - 1;
    const u16* aLo = Asrc + (size_t)(base + rlo) * kst + koff + sk;
    const u16* aHi = Asrc + (size_t)(base + rhi) * kst + koff + sk;
    const u16* bLo = Bsrc + (size_t)(n0 + srow) * kst + koff + sk;
    const u16* bHi = Bsrc + (size_t)(n0 + 128 + srow) * kst + koff + sk;

    f32x4 acc[8][4];
    #pragma unroll
    for (int i = 0; i < 8; ++i)
        #pragma unroll
        for (int j = 0; j < 4; ++j) acc[i][j] = (f32x4){0.f, 0.f, 0.f, 0.f};

    const int lane = tid & 63;
    const int wv = tid >> 6;
    const int wr = wv >> 2;
    const int wn = wv & 3;
    const int l15 = lane & 15;
    const int ksl = lane >> 4;
    int aofs[8], bofs[4];
    #pragma unroll
    for (int j = 0; j < 8; ++j) {
        int mrow = (j >> 2) * 128 + wr * 64 + (j & 3) * 16;
        aofs[j] = (mrow + l15) * 32 + ksl * 8;
    }
    #pragma unroll
    for (int i = 0; i < 4; ++i) {
        int nrow = (i >> 1) * 128 + wn * 32 + (i & 1) * 16;
        bofs[i] = (nrow + l15) * 32 + ksl * 8;
    }

    GEMM_MAIN(22)   // K-chunk = 1408

    const int l4 = ksl * 4;
    #pragma unroll
    for (int j = 0; j < 8; ++j) {
        int mrow = (j >> 2) * 128 + wr * 64 + (j & 3) * 16;
        #pragma unroll
        for (int i = 0; i < 4; ++i) {
            int nrow = (i >> 1) * 128 + wn * 32 + (i & 1) * 16;
            int c = n0 + nrow + l15;
            #pragma unroll
            for (int jj = 0; jj < 4; ++jj) {
                int r = m0 + mrow + l4 + jj;
                if (r < cnt) {
                    if (!shr)
                        DexpO[(size_t)(base + r) * HDIM + c] = acc[j][i][jj];
                    else
                        atomicAdd(&OutS[(size_t)r * HDIM + c], acc[j][i][jj]);
                }
            }
        }
    }
}

// ---------------- combine ----------------
__global__ __launch_bounds__(256) void combine_kernel(
    const float* __restrict__ Dexp,
    const int* __restrict__ slot, const float* __restrict__ topk_w,
    const float* __restrict__ sgate, float* __restrict__ Out)
{
    int idx = blockIdx.x * 256 + threadIdx.x;
    int t = idx >> 8;
    int c = (idx & 255) * 4;
    int s0 = slot[2 * t], s1 = slot[2 * t + 1];
    float w0 = topk_w[2 * t], w1 = topk_w[2 * t + 1], sg = sgate[t];
    f32x4 sh = *(const f32x4*)(Out + (size_t)t * HDIM + c);
    f32x4 d0 = *(const f32x4*)(Dexp + (size_t)s0 * HDIM + c);
    f32x4 d1 = *(const f32x4*)(Dexp + (size_t)s1 * HDIM + c);
    f32x4 o;
    #pragma unroll
    for (int j = 0; j < 4; ++j) o[j] = sg * sh[j] + w0 * d0[j] + w1 * d1[j];
    *(f32x4*)(Out + (size_t)t * HDIM + c) = o;
}

// ---------------- launch ----------------
extern "C" void kernel_launch(void* const* d_in, const int* in_sizes, int n_in,
                              void* d_out, int out_size, void* d_ws, size_t ws_size,
                              hipStream_t stream)
{
    const float* X   = (const float*)d_in[0];
    const float* GW  = (const float*)d_in[1];
    const float* WG  = (const float*)d_in[2];
    const float* WU  = (const float*)d_in[3];
    const float* WD  = (const float*)d_in[4];
    const float* SG  = (const float*)d_in[5];
    const float* SU  = (const float*)d_in[6];
    const float* SD  = (const float*)d_in[7];
    const float* SEG = (const float*)d_in[8];
    float* Out = (float*)d_out;

    char* ws = (char*)d_ws;
    int*   counts    = (int*)(ws + 0);
    int*   seg_start = (int*)(ws + 64);
    int*   cursors   = (int*)(ws + 128);
    int*   topk_e    = (int*)(ws + 1024);
    float* topk_w    = (float*)(ws + 1024 + 32768);
    float* sgate     = (float*)(ws + 1024 + 65536);
    int*   tok_ids   = (int*)(ws + 1024 + 65536 + 16384);
    int*   slot      = (int*)(ws + 1024 + 65536 + 16384 + 32768);

    u16* Xbf  = (u16*)(ws + 0x40000ull);     // 8.4 MB
    u16* Hact = (u16*)(ws + 0xA00000ull);    // 23.1 MB ([8192][1408])
    u16* Hs   = (u16*)(ws + 0x2200000ull);   // 23.1 MB ([4096][2816])
    u16* WGUc = (u16*)(ws + 0x3A00000ull);   // 46.1 MB (8 x interleaved [2816][1024])
    u16* WDt  = (u16*)(ws + 0x6900000ull);   // 23.1 MB (8 x [1024][1408])
    u16* SGUc = (u16*)(ws + 0x8100000ull);   // 11.5 MB (interleaved [5632][1024])
    u16* SDt  = (u16*)(ws + 0x8D00000ull);   // 5.8 MB ([1024][2816])
    // Dexp aliases WGUc (33.5 MB <= 46.1 MB); written only after gemm_gu done
    float* Dexp = (float*)(ws + 0x3A00000ull);

    hipMemsetAsync(counts, 0, 64, stream);
    hipMemsetAsync(Out, 0, (size_t)T_TOK * HDIM * sizeof(float), stream);

    // routing
    route_kernel<<<T_TOK / 4, 256, 0, stream>>>(X, GW, SEG, topk_e, topk_w, sgate);
    hist_kernel<<<(T_TOK * 2) / 256, 256, 0, stream>>>(topk_e, counts);
    offsets_kernel<<<1, 64, 0, stream>>>(counts, seg_start, cursors);
    scatter_kernel<<<(T_TOK * 2) / 256, 256, 0, stream>>>(topk_e, cursors, tok_ids, slot);

    // converts
    cvt_x_kernel<<<(T_TOK * HDIM) / (256 * 8), 256, 0, stream>>>(X, Xbf, T_TOK * HDIM);
    transpose_cvt<<<dim3(IDIM / 64, HDIM / 64, 2 * NEXP), 256, 0, stream>>>(WG, WU, WGUc, HDIM, IDIM, NEXP, 1);
    transpose_cvt<<<dim3(HDIM / 64, IDIM / 64, NEXP), 256, 0, stream>>>(WD, WD, WDt, IDIM, HDIM, NEXP, 0);
    transpose_cvt<<<dim3(ISDIM / 64, HDIM / 64, 2), 256, 0, stream>>>(SG, SU, SGUc, HDIM, ISDIM, 1, 1);
    transpose_cvt<<<dim3(HDIM / 64, ISDIM / 64, 1), 256, 0, stream>>>(SD, SD, SDt, ISDIM, HDIM, 1, 0);

    // merged gate+up (expert zz<88 XCD-pinned, shared zz>=88)
    gemm_gu<<<dim3(110, 16), 512, 131072, stream>>>(
        Xbf, WGUc, SGUc, Hact, Hs,
        tok_ids, seg_start, counts);

    // merged balanced down: expert -> Dexp (store), shared k-chunks -> Out (atomicAdd)
    gemm_down<<<dim3(40, 16), 512, 131072, stream>>>(
        Hact, Hs, WDt, SDt, Dexp, Out,
        seg_start, counts);

    // final combine
    combine_kernel<<<(T_TOK * HDIM / 4) / 256, 256, 0, stream>>>(
        Dexp, slot, topk_w, sgate, Out);
}

// Round 11
// 347.833 us; speedup vs baseline: 1.0287x; 1.0287x over previous
//
#include <hip/hip_runtime.h>
#include <hip/hip_bf16.h>

#define T_TOK 4096
#define HDIM  1024
#define NEXP  8
#define IDIM  1408
#define ISDIM 2816

typedef short bf16x8 __attribute__((ext_vector_type(8)));
typedef float f32x4  __attribute__((ext_vector_type(4)));
typedef unsigned short u16;
typedef unsigned short u16x4 __attribute__((ext_vector_type(4)));
typedef unsigned short u16x8 __attribute__((ext_vector_type(8)));

typedef __attribute__((address_space(1))) const void gvoid;
typedef __attribute__((address_space(3))) void lvoid;

__device__ __forceinline__ u16 f2bf(float f) {
    union { float f; unsigned u; } c; c.f = f;
    unsigned r = (c.u + 0x7FFFu + ((c.u >> 16) & 1u)) >> 16;
    return (u16)r;
}
__device__ __forceinline__ float bf2f(u16 v) {
    union { unsigned u; float f; } c; c.u = (unsigned)v << 16; return c.f;
}
__device__ __forceinline__ void glds16(const u16* g, u16* l) {
    __builtin_amdgcn_global_load_lds((gvoid*)g, (lvoid*)l, 16, 0, 0);
}

// ---------------- routing: one wave per token (no atomics) ----------------
__global__ __launch_bounds__(256) void route_kernel(
    const float* __restrict__ X, const float* __restrict__ GW,
    const float* __restrict__ SEG,
    int* __restrict__ topk_e, float* __restrict__ topk_w,
    float* __restrict__ sgate)
{
    const int t = blockIdx.x * 4 + (threadIdx.x >> 6);
    const int lane = threadIdx.x & 63;
    float acc[NEXP];
    #pragma unroll
    for (int e = 0; e < NEXP; ++e) acc[e] = 0.f;
    float sacc = 0.f;
    const float* xr = X + (size_t)t * HDIM;
    for (int h = lane; h < HDIM; h += 64) {
        float xv = xr[h];
        f32x4 g0 = *(const f32x4*)(GW + (size_t)h * NEXP);
        f32x4 g1 = *(const f32x4*)(GW + (size_t)h * NEXP + 4);
        acc[0] += xv * g0[0]; acc[1] += xv * g0[1];
        acc[2] += xv * g0[2]; acc[3] += xv * g0[3];
        acc[4] += xv * g1[0]; acc[5] += xv * g1[1];
        acc[6] += xv * g1[2]; acc[7] += xv * g1[3];
        sacc += xv * SEG[h];
    }
    #pragma unroll
    for (int off = 32; off > 0; off >>= 1) {
        #pragma unroll
        for (int e = 0; e < NEXP; ++e) acc[e] += __shfl_down(acc[e], off);
        sacc += __shfl_down(sacc, off);
    }
    if (lane == 0) {
        int e0 = 0;
        #pragma unroll
        for (int e = 1; e < NEXP; ++e) if (acc[e] > acc[e0]) e0 = e;
        int e1 = (e0 == 0) ? 1 : 0;
        #pragma unroll
        for (int e = 0; e < NEXP; ++e)
            if (e != e0 && acc[e] > acc[e1]) e1 = e;
        float w0 = 1.f / (1.f + __expf(acc[e1] - acc[e0]));
        topk_e[t * 2]     = e0; topk_e[t * 2 + 1] = e1;
        topk_w[t * 2]     = w0; topk_w[t * 2 + 1] = 1.f - w0;
        sgate[t] = 1.f / (1.f + __expf(-sacc));
    }
}

// ---------------- histogram ----------------
__global__ __launch_bounds__(256) void hist_kernel(
    const int* __restrict__ topk_e, int* __restrict__ counts)
{
    __shared__ int h[NEXP];
    if (threadIdx.x < NEXP) h[threadIdx.x] = 0;
    __syncthreads();
    int i = blockIdx.x * 256 + threadIdx.x;
    atomicAdd(&h[topk_e[i]], 1);
    __syncthreads();
    if (threadIdx.x < NEXP) atomicAdd(&counts[threadIdx.x], h[threadIdx.x]);
}

__global__ void offsets_kernel(const int* __restrict__ counts,
                               int* __restrict__ seg_start,
                               int* __restrict__ cursors)
{
    if (threadIdx.x == 0) {
        int s = 0;
        for (int e = 0; e < NEXP; ++e) {
            seg_start[e] = s; cursors[e] = s; s += counts[e];
        }
    }
}

// ---------------- scatter ----------------
__global__ __launch_bounds__(256) void scatter_kernel(
    const int* __restrict__ topk_e,
    int* __restrict__ cursors, int* __restrict__ tok_ids,
    int* __restrict__ slot)
{
    const int i = blockIdx.x * 256 + threadIdx.x;
    const int lane = threadIdx.x & 63;
    const int e = topk_e[i];
    const unsigned long long lt = (1ull << lane) - 1ull;
    #pragma unroll
    for (int ex = 0; ex < NEXP; ++ex) {
        unsigned long long mask = __ballot(e == ex);
        if (mask == 0ull) continue;
        int cnt = __popcll(mask);
        int leader = __ffsll((long long)mask) - 1;
        int base_ = 0;
        if (lane == leader) base_ = atomicAdd(&cursors[ex], cnt);
        base_ = __shfl(base_, leader);
        if (e == ex) {
            int pos = base_ + __popcll(mask & lt);
            tok_ids[pos] = i >> 1;
            slot[i] = pos;
        }
    }
}

// ---------------- converts ----------------
__global__ __launch_bounds__(256) void cvt_x_kernel(
    const float* __restrict__ in, u16* __restrict__ out, int n)
{
    int i = (blockIdx.x * 256 + threadIdx.x) * 8;
    if (i < n) {
        f32x4 a = *(const f32x4*)(in + i);
        f32x4 b = *(const f32x4*)(in + i + 4);
        u16x8 o;
        #pragma unroll
        for (int j = 0; j < 4; ++j) { o[j] = f2bf(a[j]); o[j + 4] = f2bf(b[j]); }
        *(u16x8*)(out + i) = o;
    }
}

// fp32 [K][N] slices -> bf16 [N][K] (ilv=0) or 16-row gate/up interleave (ilv=1)
__global__ __launch_bounds__(256) void transpose_cvt(
    const float* __restrict__ in0, const float* __restrict__ in1,
    u16* __restrict__ out, int K, int N, int split, int ilv)
{
    const int z = blockIdx.z;
    const int e = (z < split) ? z : z - split;
    const float* in = (z < split) ? (in0 + (size_t)z * K * N)
                                  : (in1 + (size_t)(z - split) * K * N);
    u16* o = ilv ? (out + (size_t)e * 2 * N * K)
                 : (out + (size_t)z * N * K);
    const int radd = ilv ? ((z < split) ? 0 : 16) : 0;

    __shared__ float tile[64][65];
    const int n0 = blockIdx.x * 64, k0 = blockIdx.y * 64;
    const int tx = threadIdx.x & 15;
    const int ty = threadIdx.x >> 4;

    #pragma unroll
    for (int p = 0; p < 4; ++p) {
        int k = ty + p * 16;
        f32x4 v = *(const f32x4*)(in + (size_t)(k0 + k) * N + n0 + tx * 4);
        *(f32x4*)&tile[k][tx * 4] = v;
    }
    __syncthreads();
    #pragma unroll
    for (int p = 0; p < 4; ++p) {
        int n = ty + p * 16;
        u16x4 w;
        #pragma unroll
        for (int j = 0; j < 4; ++j) w[j] = f2bf(tile[tx * 4 + j][n]);
        int R = n0 + n;
        int orow = ilv ? (((R >> 4) * 32) + (R & 15) + radd) : R;
        *(u16x4*)(o + (size_t)(n0 + n) * K + k0 + tx * 4 - (size_t)(n0 + n) * K + (size_t)orow * K) = w;
    }
}

// ====== 256x256xBK64, 8 waves, 4-phase/K-tile, granule-swizzled LDS ======
// LDS: A [2 buf][2 kh][256 rows][32 k] = 64KB, B same (dynamic 128KB).
// Swizzle: LDS slot (row, s) holds global 16B-granule s ^ ((row>>1)&3).
//   Stage (dest linear tid*16B): global k-offset = ((tid&3)^((tid>>3)&3))*8 u16.
//   Read (row r, granule ks):   u16 offset r*32 + ((ks^((r>>1)&3))*8); for
//   fragment rows (multiples of 16 + l15) this is r*32 + ((ks^((l15>>1)&3))*8).

#define BAR() __builtin_amdgcn_s_barrier()
#define WCNT(n) asm volatile("s_waitcnt vmcnt(" #n ")" ::: "memory")

#define GSTAGE_KH0(wb) \
    glds16(aLo, &As[(wb) + tid * 8]); \
    glds16(aHi, &As[(wb) + 4096 + tid * 8]); \
    glds16(bLo, &Bs[(wb) + tid * 8]); \
    glds16(bHi, &Bs[(wb) + 4096 + tid * 8]);
#define GSTAGE_KH1(wb) \
    glds16(aLo + 32, &As[(wb) + 8192 + tid * 8]); \
    glds16(aHi + 32, &As[(wb) + 8192 + 4096 + tid * 8]); \
    glds16(bLo + 32, &Bs[(wb) + 8192 + tid * 8]); \
    glds16(bHi + 32, &Bs[(wb) + 8192 + 4096 + tid * 8]);

#define RD_A(rb, kh, j0) \
    _Pragma("unroll") for (int q = 0; q < 4; ++q) \
        av[q] = *(const bf16x8*)&As[(rb) + (kh) * 8192 + aofs[(j0) + q]];
#define RD_B(rb, kh) \
    _Pragma("unroll") for (int q = 0; q < 4; ++q) \
        bv[q] = *(const bf16x8*)&Bs[(rb) + (kh) * 8192 + bofs[q]];
#define MF16(ms) \
    __builtin_amdgcn_s_setprio(1); \
    _Pragma("unroll") for (int q = 0; q < 4; ++q) \
        _Pragma("unroll") for (int w = 0; w < 4; ++w) \
            acc[(ms) + q][w] = __builtin_amdgcn_mfma_f32_16x16x32_bf16(av[q], bv[w], acc[(ms) + q][w], 0, 0, 0); \
    __builtin_amdgcn_s_setprio(0);

#define GEMM_MAIN(NT) \
    GSTAGE_KH0(0) GSTAGE_KH1(0) \
    aLo += 64; aHi += 64; bLo += 64; bHi += 64; \
    WCNT(4); BAR(); \
    _Pragma("unroll 1") \
    for (int t = 0; t < (NT) - 1; ++t) { \
        const int rb = (t & 1) * 16384, wb = rb ^ 16384; \
        bf16x8 av[4], bv[4]; \
        RD_A(rb, 0, 0) RD_B(rb, 0) \
        GSTAGE_KH0(wb) \
        BAR(); MF16(0) BAR(); \
        RD_A(rb, 0, 4) \
        GSTAGE_KH1(wb) \
        BAR(); MF16(4) WCNT(8); BAR(); \
        RD_A(rb, 1, 0) RD_B(rb, 1) \
        BAR(); MF16(0) BAR(); \
        RD_A(rb, 1, 4) \
        BAR(); MF16(4) WCNT(4); BAR(); \
        aLo += 64; aHi += 64; bLo += 64; bHi += 64; \
    } \
    { \
        const int rb = (((NT) - 1) & 1) * 16384; \
        bf16x8 av[4], bv[4]; \
        RD_A(rb, 0, 0) RD_B(rb, 0) \
        BAR(); MF16(0) BAR(); \
        RD_A(rb, 0, 4) \
        BAR(); MF16(4) WCNT(0); BAR(); \
        RD_A(rb, 1, 0) RD_B(rb, 1) \
        BAR(); MF16(0) BAR(); \
        RD_A(rb, 1, 4) \
        BAR(); MF16(4) \
    }

// ---------------- merged gate+up GEMM (interleaved combined weights [2N][K]) ----------------
// grid(112, 16): zz<88 expert (e=zz&7, nz=zz>>3 of 11); zz in [88,110) shared; pad >=110.
// 112 % 8 == 0 keeps flat_id%8 == zz%8 -> expert e pinned to XCD e.
__global__ __launch_bounds__(512, 2) void gemm_gu(
    const u16* __restrict__ A,
    const u16* __restrict__ WGUc, const u16* __restrict__ SGUc,
    u16* __restrict__ HoutE, u16* __restrict__ HoutS,
    const int* __restrict__ a_ids, const int* __restrict__ seg_start,
    const int* __restrict__ counts)
{
    extern __shared__ u16 lds[];
    u16* As = lds;
    u16* Bs = lds + 32768;

    const int zz = blockIdx.x;
    if (zz >= 110) return;
    int cnt, base, n0c, N, nblk;
    const u16* Bsrc;
    u16* Hout;
    const int* ids;
    if (zz < 88) {
        int e = zz & 7;
        nblk = zz >> 3;
        cnt = counts[e]; base = seg_start[e];
        Bsrc = WGUc + (size_t)e * (2 * IDIM * HDIM);
        Hout = HoutE; N = IDIM; ids = a_ids;
    } else {
        nblk = zz - 88;
        cnt = T_TOK; base = 0;
        Bsrc = SGUc; Hout = HoutS; N = ISDIM; ids = nullptr;
    }
    n0c = nblk * 256;
    const int m0 = blockIdx.y * 256;
    if (m0 >= cnt) return;

    const int tid = threadIdx.x;
    const int srow = tid >> 2;
    const int sk = (((tid & 3) ^ ((tid >> 3) & 3))) * 8;   // swizzled source granule
    int rlo = m0 + srow;       if (rlo >= cnt) rlo = cnt - 1;
    int rhi = m0 + 128 + srow; if (rhi >= cnt) rhi = cnt - 1;
    const int glo = ids ? ids[base + rlo] : (base + rlo);
    const int ghi = ids ? ids[base + rhi] : (base + rhi);
    const u16* aLo = A + (size_t)glo * HDIM + sk;
    const u16* aHi = A + (size_t)ghi * HDIM + sk;
    const u16* bLo = Bsrc + (size_t)(n0c + srow) * HDIM + sk;
    const u16* bHi = Bsrc + (size_t)(n0c + 128 + srow) * HDIM + sk;

    f32x4 acc[8][4];
    #pragma unroll
    for (int i = 0; i < 8; ++i)
        #pragma unroll
        for (int j = 0; j < 4; ++j) acc[i][j] = (f32x4){0.f, 0.f, 0.f, 0.f};

    const int lane = tid & 63;
    const int wv = tid >> 6;
    const int wr = wv >> 2;
    const int wn = wv & 3;
    const int l15 = lane & 15;
    const int ksl = lane >> 4;
    const int kswz = ((ksl ^ ((l15 >> 1) & 3))) * 8;       // swizzled read granule
    int aofs[8], bofs[4];
    #pragma unroll
    for (int j = 0; j < 8; ++j) {
        int mrow = (j >> 2) * 128 + wr * 64 + (j & 3) * 16;
        aofs[j] = (mrow + l15) * 32 + kswz;
    }
    #pragma unroll
    for (int i = 0; i < 4; ++i) {
        int nrow = (i >> 1) * 128 + wn * 32 + (i & 1) * 16;
        bofs[i] = (nrow + l15) * 32 + kswz;
    }

    GEMM_MAIN(16)   // K = 1024

    const int l4 = ksl * 4;
    #pragma unroll
    for (int j = 0; j < 8; ++j) {
        int mrow = (j >> 2) * 128 + wr * 64 + (j & 3) * 16;
        #pragma unroll
        for (int p = 0; p < 2; ++p) {
            f32x4 g = acc[j][2 * p], u = acc[j][2 * p + 1];
            int c = nblk * 128 + (p * 4 + wn) * 16 + l15;
            #pragma unroll
            for (int jj = 0; jj < 4; ++jj) {
                int r = m0 + mrow + l4 + jj;
                if (r < cnt) {
                    float hv = g[jj] / (1.f + __expf(-g[jj])) * u[jj];
                    Hout[(size_t)(base + r) * N + c] = f2bf(hv);
                }
            }
        }
    }
}

// ---------------- down GEMM 256x256: grid(40, 16) (40 % 8 == 0, affinity kept) ----------------
// zz<32: expert (e=zz&7, n=(zz>>3)*256, K=1408, A=Hact) -> store Dexp
// zz in [32,40): shared (idx=zz-32: n=(idx&3)*256, kc=idx>>2) -> atomicAdd Out
__global__ __launch_bounds__(512, 2) void gemm_down(
    const u16* __restrict__ AE, const u16* __restrict__ AS,
    const u16* __restrict__ WDt, const u16* __restrict__ SDt,
    float* __restrict__ DexpO, float* __restrict__ OutS,
    const int* __restrict__ seg_start, const int* __restrict__ counts)
{
    extern __shared__ u16 lds[];
    u16* As = lds;
    u16* Bs = lds + 32768;

    const int zz = blockIdx.x;
    const bool shr = (zz >= 32);
    int n0, cnt, base, kst;
    size_t koff;
    const u16 *Asrc, *Bsrc;
    if (!shr) {
        int e = zz & 7;
        n0 = (zz >> 3) * 256;
        cnt = counts[e]; base = seg_start[e];
        Asrc = AE; Bsrc = WDt + (size_t)e * (HDIM * IDIM);
        kst = IDIM; koff = 0;
    } else {
        int idx = zz - 32;
        n0 = (idx & 3) * 256;
        cnt = T_TOK; base = 0;
        Asrc = AS; Bsrc = SDt;
        kst = ISDIM; koff = (size_t)(idx >> 2) * 1408;
    }
    const int m0 = blockIdx.y * 256;
    if (m0 >= cnt) return;

    const int tid = threadIdx.x;
    const int srow = tid >> 2;
    const int sk = (((tid & 3) ^ ((tid >> 3) & 3))) * 8;
    int rlo = m0 + srow;       if (rlo >= cnt) rlo = cnt - 1;
    int rhi = m0 + 128 + srow; if (rhi >= cnt) rhi = cnt - 1;
    const u16* aLo = Asrc + (size_t)(base + rlo) * kst + koff + sk;
    const u16* aHi = Asrc + (size_t)(base + rhi) * kst + koff + sk;
    const u16* bLo = Bsrc + (size_t)(n0 + srow) * kst + koff + sk;
    const u16* bHi = Bsrc + (size_t)(n0 + 128 + srow) * kst + koff + sk;

    f32x4 acc[8][4];
    #pragma unroll
    for (int i = 0; i < 8; ++i)
        #pragma unroll
        for (int j = 0; j < 4; ++j) acc[i][j] = (f32x4){0.f, 0.f, 0.f, 0.f};

    const int lane = tid & 63;
    const int wv = tid >> 6;
    const int wr = wv >> 2;
    const int wn = wv & 3;
    const int l15 = lane & 15;
    const int ksl = lane >> 4;
    const int kswz = ((ksl ^ ((l15 >> 1) & 3))) * 8;
    int aofs[8], bofs[4];
    #pragma unroll
    for (int j = 0; j < 8; ++j) {
        int mrow = (j >> 2) * 128 + wr * 64 + (j & 3) * 16;
        aofs[j] = (mrow + l15) * 32 + kswz;
    }
    #pragma unroll
    for (int i = 0; i < 4; ++i) {
        int nrow = (i >> 1) * 128 + wn * 32 + (i & 1) * 16;
        bofs[i] = (nrow + l15) * 32 + kswz;
    }

    GEMM_MAIN(22)   // K-chunk = 1408

    const int l4 = ksl * 4;
    #pragma unroll
    for (int j = 0; j < 8; ++j) {
        int mrow = (j >> 2) * 128 + wr * 64 + (j & 3) * 16;
        #pragma unroll
        for (int i = 0; i < 4; ++i) {
            int nrow = (i >> 1) * 128 + wn * 32 + (i & 1) * 16;
            int c = n0 + nrow + l15;
            #pragma unroll
            for (int jj = 0; jj < 4; ++jj) {
                int r = m0 + mrow + l4 + jj;
                if (r < cnt) {
                    if (!shr)
                        DexpO[(size_t)(base + r) * HDIM + c] = acc[j][i][jj];
                    else
                        atomicAdd(&OutS[(size_t)r * HDIM + c], acc[j][i][jj]);
                }
            }
        }
    }
}

// ---------------- combine ----------------
__global__ __launch_bounds__(256) void combine_kernel(
    const float* __restrict__ Dexp,
    const int* __restrict__ slot, const float* __restrict__ topk_w,
    const float* __restrict__ sgate, float* __restrict__ Out)
{
    int idx = blockIdx.x * 256 + threadIdx.x;
    int t = idx >> 8;
    int c = (idx & 255) * 4;
    int s0 = slot[2 * t], s1 = slot[2 * t + 1];
    float w0 = topk_w[2 * t], w1 = topk_w[2 * t + 1], sg = sgate[t];
    f32x4 sh = *(const f32x4*)(Out + (size_t)t * HDIM + c);
    f32x4 d0 = *(const f32x4*)(Dexp + (size_t)s0 * HDIM + c);
    f32x4 d1 = *(const f32x4*)(Dexp + (size_t)s1 * HDIM + c);
    f32x4 o;
    #pragma unroll
    for (int j = 0; j < 4; ++j) o[j] = sg * sh[j] + w0 * d0[j] + w1 * d1[j];
    *(f32x4*)(Out + (size_t)t * HDIM + c) = o;
}

// ---------------- launch ----------------
extern "C" void kernel_launch(void* const* d_in, const int* in_sizes, int n_in,
                              void* d_out, int out_size, void* d_ws, size_t ws_size,
                              hipStream_t stream)
{
    const float* X   = (const float*)d_in[0];
    const float* GW  = (const float*)d_in[1];
    const float* WG  = (const float*)d_in[2];
    const float* WU  = (const float*)d_in[3];
    const float* WD  = (const float*)d_in[4];
    const float* SG  = (const float*)d_in[5];
    const float* SU  = (const float*)d_in[6];
    const float* SD  = (const float*)d_in[7];
    const float* SEG = (const float*)d_in[8];
    float* Out = (float*)d_out;

    char* ws = (char*)d_ws;
    int*   counts    = (int*)(ws + 0);
    int*   seg_start = (int*)(ws + 64);
    int*   cursors   = (int*)(ws + 128);
    int*   topk_e    = (int*)(ws + 1024);
    float* topk_w    = (float*)(ws + 1024 + 32768);
    float* sgate     = (float*)(ws + 1024 + 65536);
    int*   tok_ids   = (int*)(ws + 1024 + 65536 + 16384);
    int*   slot      = (int*)(ws + 1024 + 65536 + 16384 + 32768);

    u16* Xbf  = (u16*)(ws + 0x40000ull);     // 8.4 MB
    u16* Hact = (u16*)(ws + 0xA00000ull);    // 23.1 MB ([8192][1408])
    u16* Hs   = (u16*)(ws + 0x2200000ull);   // 23.1 MB ([4096][2816])
    u16* WGUc = (u16*)(ws + 0x3A00000ull);   // 46.1 MB (8 x interleaved [2816][1024])
    u16* WDt  = (u16*)(ws + 0x6900000ull);   // 23.1 MB (8 x [1024][1408])
    u16* SGUc = (u16*)(ws + 0x8100000ull);   // 11.5 MB (interleaved [5632][1024])
    u16* SDt  = (u16*)(ws + 0x8D00000ull);   // 5.8 MB ([1024][2816])
    // Dexp aliases WGUc (33.5 MB <= 46.1 MB); written only after gemm_gu done
    float* Dexp = (float*)(ws + 0x3A00000ull);

    hipMemsetAsync(counts, 0, 64, stream);
    hipMemsetAsync(Out, 0, (size_t)T_TOK * HDIM * sizeof(float), stream);

    // routing
    route_kernel<<<T_TOK / 4, 256, 0, stream>>>(X, GW, SEG, topk_e, topk_w, sgate);
    hist_kernel<<<(T_TOK * 2) / 256, 256, 0, stream>>>(topk_e, counts);
    offsets_kernel<<<1, 64, 0, stream>>>(counts, seg_start, cursors);
    scatter_kernel<<<(T_TOK * 2) / 256, 256, 0, stream>>>(topk_e, cursors, tok_ids, slot);

    // converts
    cvt_x_kernel<<<(T_TOK * HDIM) / (256 * 8), 256, 0, stream>>>(X, Xbf, T_TOK * HDIM);
    transpose_cvt<<<dim3(IDIM / 64, HDIM / 64, 2 * NEXP), 256, 0, stream>>>(WG, WU, WGUc, HDIM, IDIM, NEXP, 1);
    transpose_cvt<<<dim3(HDIM / 64, IDIM / 64, NEXP), 256, 0, stream>>>(WD, WD, WDt, IDIM, HDIM, NEXP, 0);
    transpose_cvt<<<dim3(ISDIM / 64, HDIM / 64, 2), 256, 0, stream>>>(SG, SU, SGUc, HDIM, ISDIM, 1, 1);
    transpose_cvt<<<dim3(HDIM / 64, ISDIM / 64, 1), 256, 0, stream>>>(SD, SD, SDt, ISDIM, HDIM, 1, 0);

    // merged gate+up (grid x padded to 112 -> expert/XCD affinity preserved)
    gemm_gu<<<dim3(112, 16), 512, 131072, stream>>>(
        Xbf, WGUc, SGUc, Hact, Hs,
        tok_ids, seg_start, counts);

    // merged balanced down: expert -> Dexp (store), shared k-chunks -> Out (atomicAdd)
    gemm_down<<<dim3(40, 16), 512, 131072, stream>>>(
        Hact, Hs, WDt, SDt, Dexp, Out,
        seg_start, counts);

    // final combine
    combine_kernel<<<(T_TOK * HDIM / 4) / 256, 256, 0, stream>>>(
        Dexp, slot, topk_w, sgate, Out);
}

// Round 12
// 309.183 us; speedup vs baseline: 1.1573x; 1.1250x over previous
//
#include <hip/hip_runtime.h>
#include <hip/hip_bf16.h>

#define T_TOK 4096
#define HDIM  1024
#define NEXP  8
#define IDIM  1408
#define ISDIM 2816
#define PADT  10240   // 40 tiles of 256 (worst-case padded expert rows)

typedef short bf16x8 __attribute__((ext_vector_type(8)));
typedef float f32x4  __attribute__((ext_vector_type(4)));
typedef unsigned short u16;
typedef unsigned short u16x4 __attribute__((ext_vector_type(4)));
typedef unsigned short u16x8 __attribute__((ext_vector_type(8)));

typedef __attribute__((address_space(1))) const void gvoid;
typedef __attribute__((address_space(3))) void lvoid;

__device__ __forceinline__ u16 f2bf(float f) {
    union { float f; unsigned u; } c; c.f = f;
    unsigned r = (c.u + 0x7FFFu + ((c.u >> 16) & 1u)) >> 16;
    return (u16)r;
}
__device__ __forceinline__ float bf2f(u16 v) {
    union { unsigned u; float f; } c; c.u = (unsigned)v << 16; return c.f;
}
__device__ __forceinline__ void glds16(const u16* g, u16* l) {
    __builtin_amdgcn_global_load_lds((gvoid*)g, (lvoid*)l, 16, 0, 0);
}

// ---------------- routing: one wave per token (no atomics) ----------------
__global__ __launch_bounds__(256) void route_kernel(
    const float* __restrict__ X, const float* __restrict__ GW,
    const float* __restrict__ SEG,
    int* __restrict__ topk_e, float* __restrict__ topk_w,
    float* __restrict__ sgate)
{
    const int t = blockIdx.x * 4 + (threadIdx.x >> 6);
    const int lane = threadIdx.x & 63;
    float acc[NEXP];
    #pragma unroll
    for (int e = 0; e < NEXP; ++e) acc[e] = 0.f;
    float sacc = 0.f;
    const float* xr = X + (size_t)t * HDIM;
    for (int h = lane; h < HDIM; h += 64) {
        float xv = xr[h];
        f32x4 g0 = *(const f32x4*)(GW + (size_t)h * NEXP);
        f32x4 g1 = *(const f32x4*)(GW + (size_t)h * NEXP + 4);
        acc[0] += xv * g0[0]; acc[1] += xv * g0[1];
        acc[2] += xv * g0[2]; acc[3] += xv * g0[3];
        acc[4] += xv * g1[0]; acc[5] += xv * g1[1];
        acc[6] += xv * g1[2]; acc[7] += xv * g1[3];
        sacc += xv * SEG[h];
    }
    #pragma unroll
    for (int off = 32; off > 0; off >>= 1) {
        #pragma unroll
        for (int e = 0; e < NEXP; ++e) acc[e] += __shfl_down(acc[e], off);
        sacc += __shfl_down(sacc, off);
    }
    if (lane == 0) {
        int e0 = 0;
        #pragma unroll
        for (int e = 1; e < NEXP; ++e) if (acc[e] > acc[e0]) e0 = e;
        int e1 = (e0 == 0) ? 1 : 0;
        #pragma unroll
        for (int e = 0; e < NEXP; ++e)
            if (e != e0 && acc[e] > acc[e1]) e1 = e;
        float w0 = 1.f / (1.f + __expf(acc[e1] - acc[e0]));
        topk_e[t * 2]     = e0; topk_e[t * 2 + 1] = e1;
        topk_w[t * 2]     = w0; topk_w[t * 2 + 1] = 1.f - w0;
        sgate[t] = 1.f / (1.f + __expf(-sacc));
    }
}

// ---------------- histogram ----------------
__global__ __launch_bounds__(256) void hist_kernel(
    const int* __restrict__ topk_e, int* __restrict__ counts)
{
    __shared__ int h[NEXP];
    if (threadIdx.x < NEXP) h[threadIdx.x] = 0;
    __syncthreads();
    int i = blockIdx.x * 256 + threadIdx.x;
    atomicAdd(&h[topk_e[i]], 1);
    __syncthreads();
    if (threadIdx.x < NEXP) atomicAdd(&counts[threadIdx.x], h[threadIdx.x]);
}

// seg_pad[e]: 256-aligned padded segment starts; seg_pad[8] = padded total
__global__ void offsets_kernel(const int* __restrict__ counts,
                               int* __restrict__ seg_pad,
                               int* __restrict__ cursors)
{
    if (threadIdx.x == 0) {
        int s = 0;
        for (int e = 0; e < NEXP; ++e) {
            seg_pad[e] = s; cursors[e] = s;
            s += ((counts[e] + 255) >> 8) << 8;
        }
        seg_pad[NEXP] = s;
    }
}

__global__ __launch_bounds__(256) void prefill_kernel(int* __restrict__ tok_ids)
{
    int i = blockIdx.x * 256 + threadIdx.x;
    if (i < PADT) tok_ids[i] = 0;
}

// ---------------- scatter ----------------
__global__ __launch_bounds__(256) void scatter_kernel(
    const int* __restrict__ topk_e,
    int* __restrict__ cursors, int* __restrict__ tok_ids,
    int* __restrict__ slot)
{
    const int i = blockIdx.x * 256 + threadIdx.x;
    const int lane = threadIdx.x & 63;
    const int e = topk_e[i];
    const unsigned long long lt = (1ull << lane) - 1ull;
    #pragma unroll
    for (int ex = 0; ex < NEXP; ++ex) {
        unsigned long long mask = __ballot(e == ex);
        if (mask == 0ull) continue;
        int cnt = __popcll(mask);
        int leader = __ffsll((long long)mask) - 1;
        int base_ = 0;
        if (lane == leader) base_ = atomicAdd(&cursors[ex], cnt);
        base_ = __shfl(base_, leader);
        if (e == ex) {
            int pos = base_ + __popcll(mask & lt);
            tok_ids[pos] = i >> 1;
            slot[i] = pos;
        }
    }
}

// ---------------- converts ----------------
__global__ __launch_bounds__(256) void cvt_x_kernel(
    const float* __restrict__ in, u16* __restrict__ out, int n)
{
    int i = (blockIdx.x * 256 + threadIdx.x) * 8;
    if (i < n) {
        f32x4 a = *(const f32x4*)(in + i);
        f32x4 b = *(const f32x4*)(in + i + 4);
        u16x8 o;
        #pragma unroll
        for (int j = 0; j < 4; ++j) { o[j] = f2bf(a[j]); o[j + 4] = f2bf(b[j]); }
        *(u16x8*)(out + i) = o;
    }
}

// fp32 [K][N] slices -> bf16 [N][K] (ilv=0) or 16-row gate/up interleave (ilv=1)
__global__ __launch_bounds__(256) void transpose_cvt(
    const float* __restrict__ in0, const float* __restrict__ in1,
    u16* __restrict__ out, int K, int N, int split, int ilv)
{
    const int z = blockIdx.z;
    const int e = (z < split) ? z : z - split;
    const float* in = (z < split) ? (in0 + (size_t)z * K * N)
                                  : (in1 + (size_t)(z - split) * K * N);
    u16* o = ilv ? (out + (size_t)e * 2 * N * K)
                 : (out + (size_t)z * N * K);
    const int radd = ilv ? ((z < split) ? 0 : 16) : 0;

    __shared__ float tile[64][65];
    const int n0 = blockIdx.x * 64, k0 = blockIdx.y * 64;
    const int tx = threadIdx.x & 15;
    const int ty = threadIdx.x >> 4;

    #pragma unroll
    for (int p = 0; p < 4; ++p) {
        int k = ty + p * 16;
        f32x4 v = *(const f32x4*)(in + (size_t)(k0 + k) * N + n0 + tx * 4);
        *(f32x4*)&tile[k][tx * 4] = v;
    }
    __syncthreads();
    #pragma unroll
    for (int p = 0; p < 4; ++p) {
        int n = ty + p * 16;
        u16x4 w;
        #pragma unroll
        for (int j = 0; j < 4; ++j) w[j] = f2bf(tile[tx * 4 + j][n]);
        int R = n0 + n;
        int orow = ilv ? (((R >> 4) * 32) + (R & 15) + radd) : R;
        *(u16x4*)(o + (size_t)orow * K + k0 + tx * 4) = w;
    }
}

// ===== 256x256xBK32, 16 waves (1024 thr, wave tile 64x64), dbuf, 1 barrier/tile =====
// LDS: A [2 buf][256 rows][32 k] = 32KB, B same (dynamic 64KB total).
// Granule swizzle (verified 0-conflict): slot (row, s) holds granule s^((row>>1)&3).
//   Stage: dest linear tid*16B; source k-granule ((tid&3)^((tid>>3)&3)).
//   Read:  u16 offset row*32 + ((ksl^((l15>>1)&3))*8).

#define BAR() __builtin_amdgcn_s_barrier()
#define WCNT0() asm volatile("s_waitcnt vmcnt(0)" ::: "memory")

#define GSTAGE(wb) do { \
    glds16(aP, &As[(wb) + tid * 8]); \
    glds16(bP, &Bs[(wb) + tid * 8]); \
    aP += 32; bP += 32; } while (0)

#define GEMM_TILE(rb) { \
    bf16x8 av[4], bv[4]; \
    _Pragma("unroll") for (int q = 0; q < 4; ++q) bv[q] = *(const bf16x8*)&Bs[(rb) + bofs[q]]; \
    _Pragma("unroll") for (int q = 0; q < 4; ++q) av[q] = *(const bf16x8*)&As[(rb) + aofs[q]]; \
    __builtin_amdgcn_s_setprio(1); \
    _Pragma("unroll") for (int q = 0; q < 4; ++q) \
        _Pragma("unroll") for (int w = 0; w < 4; ++w) \
            acc[q][w] = __builtin_amdgcn_mfma_f32_16x16x32_bf16(av[q], bv[w], acc[q][w], 0, 0, 0); \
    __builtin_amdgcn_s_setprio(0); }

#define GEMM_MAIN(NT) \
    GSTAGE(0); \
    _Pragma("unroll 1") \
    for (int t = 0; t < (NT) - 1; ++t) { \
        WCNT0(); BAR(); \
        GSTAGE((t & 1) ? 0 : 8192); \
        GEMM_TILE((t & 1) * 8192) \
    } \
    WCNT0(); BAR(); \
    GEMM_TILE((((NT) - 1) & 1) * 8192)

// ---------------- merged gate+up GEMM (interleaved combined weights [2N][K]) ----------------
// grid(792): zz<440 expert (widx=zz/11 m-tile, nz=zz%11); zz>=440 shared (sidx: m=sidx/22, n=sidx%22)
__global__ __launch_bounds__(1024, 4) void gemm_gu(
    const u16* __restrict__ A,
    const u16* __restrict__ WGUc, const u16* __restrict__ SGUc,
    u16* __restrict__ HoutE, u16* __restrict__ HoutS,
    const int* __restrict__ tok_ids, const int* __restrict__ seg_pad)
{
    extern __shared__ u16 lds[];
    u16* As = lds;
    u16* Bs = lds + 16384;

    const int zz = blockIdx.x;
    int m0, nblk, N;
    const u16* Bsrc;
    u16* Hout;
    bool gather;
    if (zz < 440) {
        int widx = zz / 11;
        nblk = zz - widx * 11;
        m0 = widx * 256;
        if (m0 >= seg_pad[NEXP]) return;
        int e = 0;
        while (e < 7 && m0 >= seg_pad[e + 1]) ++e;
        Bsrc = WGUc + (size_t)e * (2 * IDIM * HDIM);
        Hout = HoutE; N = IDIM; gather = true;
    } else {
        int sidx = zz - 440;
        int mz = sidx / 22;
        nblk = sidx - mz * 22;
        m0 = mz * 256;
        Bsrc = SGUc; Hout = HoutS; N = ISDIM; gather = false;
    }

    const int tid = threadIdx.x;
    const int srow = tid >> 2;
    const int sk = (((tid & 3) ^ ((tid >> 3) & 3))) * 8;
    const int arow = m0 + srow;
    const int ga = gather ? tok_ids[arow] : arow;
    const u16* aP = A + (size_t)ga * HDIM + sk;
    const u16* bP = Bsrc + (size_t)(nblk * 256 + srow) * HDIM + sk;

    f32x4 acc[4][4];
    #pragma unroll
    for (int i = 0; i < 4; ++i)
        #pragma unroll
        for (int j = 0; j < 4; ++j) acc[i][j] = (f32x4){0.f, 0.f, 0.f, 0.f};

    const int lane = tid & 63;
    const int wv = tid >> 6;
    const int wr = wv >> 2;
    const int wn = wv & 3;
    const int l15 = lane & 15;
    const int ksl = lane >> 4;
    const int kswz = ((ksl ^ ((l15 >> 1) & 3))) * 8;
    int aofs[4], bofs[4];
    #pragma unroll
    for (int q = 0; q < 4; ++q) {
        aofs[q] = (wr * 64 + q * 16 + l15) * 32 + kswz;
        bofs[q] = (wn * 64 + q * 16 + l15) * 32 + kswz;
    }

    GEMM_MAIN(32)   // K = 1024

    const int l4 = ksl * 4;
    #pragma unroll
    for (int j = 0; j < 4; ++j)
        #pragma unroll
        for (int p = 0; p < 2; ++p) {
            f32x4 g = acc[j][2 * p], u = acc[j][2 * p + 1];
            int c = nblk * 128 + (wn * 2 + p) * 16 + l15;
            #pragma unroll
            for (int jj = 0; jj < 4; ++jj) {
                int r = m0 + wr * 64 + j * 16 + l4 + jj;
                float hv = g[jj] / (1.f + __expf(-g[jj])) * u[jj];
                Hout[(size_t)r * N + c] = f2bf(hv);
            }
        }
}

// ---------------- down GEMM: grid(288) ----------------
// zz<160: expert (widx=zz/4 m-tile, nz=zz%4) -> store Dexp
// zz>=160: shared (idx: kc=idx/64, mz=(idx%64)/4, nz=idx%4) -> atomicAdd Out
__global__ __launch_bounds__(1024, 4) void gemm_down(
    const u16* __restrict__ AE, const u16* __restrict__ AS,
    const u16* __restrict__ WDt, const u16* __restrict__ SDt,
    float* __restrict__ DexpO, float* __restrict__ OutS,
    const int* __restrict__ seg_pad)
{
    extern __shared__ u16 lds[];
    u16* As = lds;
    u16* Bs = lds + 16384;

    const int zz = blockIdx.x;
    const bool shr = (zz >= 160);
    int m0, n0, kst;
    size_t koff;
    const u16 *Asrc, *Bsrc;
    if (!shr) {
        int widx = zz >> 2;
        n0 = (zz & 3) * 256;
        m0 = widx * 256;
        if (m0 >= seg_pad[NEXP]) return;
        int e = 0;
        while (e < 7 && m0 >= seg_pad[e + 1]) ++e;
        Asrc = AE; Bsrc = WDt + (size_t)e * (HDIM * IDIM);
        kst = IDIM; koff = 0;
    } else {
        int idx = zz - 160;
        int kc = idx >> 6;
        int rem = idx & 63;
        m0 = (rem >> 2) * 256;
        n0 = (rem & 3) * 256;
        Asrc = AS; Bsrc = SDt;
        kst = ISDIM; koff = (size_t)kc * 1408;
    }

    const int tid = threadIdx.x;
    const int srow = tid >> 2;
    const int sk = (((tid & 3) ^ ((tid >> 3) & 3))) * 8;
    const u16* aP = Asrc + (size_t)(m0 + srow) * kst + koff + sk;
    const u16* bP = Bsrc + (size_t)(n0 + srow) * kst + koff + sk;

    f32x4 acc[4][4];
    #pragma unroll
    for (int i = 0; i < 4; ++i)
        #pragma unroll
        for (int j = 0; j < 4; ++j) acc[i][j] = (f32x4){0.f, 0.f, 0.f, 0.f};

    const int lane = tid & 63;
    const int wv = tid >> 6;
    const int wr = wv >> 2;
    const int wn = wv & 3;
    const int l15 = lane & 15;
    const int ksl = lane >> 4;
    const int kswz = ((ksl ^ ((l15 >> 1) & 3))) * 8;
    int aofs[4], bofs[4];
    #pragma unroll
    for (int q = 0; q < 4; ++q) {
        aofs[q] = (wr * 64 + q * 16 + l15) * 32 + kswz;
        bofs[q] = (wn * 64 + q * 16 + l15) * 32 + kswz;
    }

    GEMM_MAIN(44)   // K-chunk = 1408

    const int l4 = ksl * 4;
    #pragma unroll
    for (int j = 0; j < 4; ++j)
        #pragma unroll
        for (int i = 0; i < 4; ++i) {
            int c = n0 + wn * 64 + i * 16 + l15;
            #pragma unroll
            for (int jj = 0; jj < 4; ++jj) {
                int r = m0 + wr * 64 + j * 16 + l4 + jj;
                if (!shr)
                    DexpO[(size_t)r * HDIM + c] = acc[j][i][jj];
                else
                    atomicAdd(&OutS[(size_t)r * HDIM + c], acc[j][i][jj]);
            }
        }
}

// ---------------- combine ----------------
__global__ __launch_bounds__(256) void combine_kernel(
    const float* __restrict__ Dexp,
    const int* __restrict__ slot, const float* __restrict__ topk_w,
    const float* __restrict__ sgate, float* __restrict__ Out)
{
    int idx = blockIdx.x * 256 + threadIdx.x;
    int t = idx >> 8;
    int c = (idx & 255) * 4;
    int s0 = slot[2 * t], s1 = slot[2 * t + 1];
    float w0 = topk_w[2 * t], w1 = topk_w[2 * t + 1], sg = sgate[t];
    f32x4 sh = *(const f32x4*)(Out + (size_t)t * HDIM + c);
    f32x4 d0 = *(const f32x4*)(Dexp + (size_t)s0 * HDIM + c);
    f32x4 d1 = *(const f32x4*)(Dexp + (size_t)s1 * HDIM + c);
    f32x4 o;
    #pragma unroll
    for (int j = 0; j < 4; ++j) o[j] = sg * sh[j] + w0 * d0[j] + w1 * d1[j];
    *(f32x4*)(Out + (size_t)t * HDIM + c) = o;
}

// ---------------- launch ----------------
extern "C" void kernel_launch(void* const* d_in, const int* in_sizes, int n_in,
                              void* d_out, int out_size, void* d_ws, size_t ws_size,
                              hipStream_t stream)
{
    const float* X   = (const float*)d_in[0];
    const float* GW  = (const float*)d_in[1];
    const float* WG  = (const float*)d_in[2];
    const float* WU  = (const float*)d_in[3];
    const float* WD  = (const float*)d_in[4];
    const float* SG  = (const float*)d_in[5];
    const float* SU  = (const float*)d_in[6];
    const float* SD  = (const float*)d_in[7];
    const float* SEG = (const float*)d_in[8];
    float* Out = (float*)d_out;

    char* ws = (char*)d_ws;
    int*   counts    = (int*)(ws + 0);
    int*   seg_pad   = (int*)(ws + 64);
    int*   cursors   = (int*)(ws + 128);
    int*   topk_e    = (int*)(ws + 1024);
    float* topk_w    = (float*)(ws + 1024 + 32768);
    float* sgate     = (float*)(ws + 1024 + 65536);
    int*   slot      = (int*)(ws + 1024 + 65536 + 16384);
    int*   tok_ids   = (int*)(ws + 1024 + 65536 + 16384 + 32768);   // 10240 ints

    u16* Xbf  = (u16*)(ws + 0x0040000ull);   // 8.39 MB
    u16* Hact = (u16*)(ws + 0x0840000ull);   // 10240x1408 bf16 = 28.8 MB
    u16* Hs   = (u16*)(ws + 0x23C0000ull);   // 4096x2816 bf16 = 23.1 MB
    u16* WGUc = (u16*)(ws + 0x39C0000ull);   // 8 x ilv [2816][1024] = 46.1 MB
    u16* WDt  = (u16*)(ws + 0x65C0000ull);   // 8 x [1024][1408] = 23.1 MB
    u16* SGUc = (u16*)(ws + 0x7BC0000ull);   // ilv [5632][1024] = 11.5 MB
    u16* SDt  = (u16*)(ws + 0x86C0000ull);   // [1024][2816] = 5.8 MB
    // Dexp (10240x1024 f32 = 41.9 MB) aliases WGUc (46.1 MB), written after gemm_gu
    float* Dexp = (float*)(ws + 0x39C0000ull);

    hipMemsetAsync(counts, 0, 64, stream);
    hipMemsetAsync(Out, 0, (size_t)T_TOK * HDIM * sizeof(float), stream);

    // routing
    route_kernel<<<T_TOK / 4, 256, 0, stream>>>(X, GW, SEG, topk_e, topk_w, sgate);
    hist_kernel<<<(T_TOK * 2) / 256, 256, 0, stream>>>(topk_e, counts);
    offsets_kernel<<<1, 64, 0, stream>>>(counts, seg_pad, cursors);
    prefill_kernel<<<PADT / 256, 256, 0, stream>>>(tok_ids);
    scatter_kernel<<<(T_TOK * 2) / 256, 256, 0, stream>>>(topk_e, cursors, tok_ids, slot);

    // converts
    cvt_x_kernel<<<(T_TOK * HDIM) / (256 * 8), 256, 0, stream>>>(X, Xbf, T_TOK * HDIM);
    transpose_cvt<<<dim3(IDIM / 64, HDIM / 64, 2 * NEXP), 256, 0, stream>>>(WG, WU, WGUc, HDIM, IDIM, NEXP, 1);
    transpose_cvt<<<dim3(HDIM / 64, IDIM / 64, NEXP), 256, 0, stream>>>(WD, WD, WDt, IDIM, HDIM, NEXP, 0);
    transpose_cvt<<<dim3(ISDIM / 64, HDIM / 64, 2), 256, 0, stream>>>(SG, SU, SGUc, HDIM, ISDIM, 1, 1);
    transpose_cvt<<<dim3(HDIM / 64, ISDIM / 64, 1), 256, 0, stream>>>(SD, SD, SDt, ISDIM, HDIM, 1, 0);

    // merged gate+up: expert (40 padded m-tiles x 11 n) + shared (16 x 22)
    gemm_gu<<<792, 1024, 65536, stream>>>(
        Xbf, WGUc, SGUc, Hact, Hs, tok_ids, seg_pad);

    // merged down: expert (40 x 4) -> Dexp, shared (2 kc x 16 x 4) -> atomicAdd Out
    gemm_down<<<288, 1024, 65536, stream>>>(
        Hact, Hs, WDt, SDt, Dexp, Out, seg_pad);

    // final combine
    combine_kernel<<<(T_TOK * HDIM / 4) / 256, 256, 0, stream>>>(
        Dexp, slot, topk_w, sgate, Out);
}